// Round 6
// baseline (332.322 us; speedup 1.0000x reference)
//
#include <hip/hip_runtime.h>

// EdgeSageLayer on MI355X — round 13.
// agg[n] = (sum_{e:dst=n} concat(x[src_e], ea_e)) @ msg_w / deg + msg_b*(deg>0)
// R12 postmortem: finalize_v5 (node-per-lane + SGPR weights) = 90us, VALU 7.7%,
// occ 13%, FETCH 16MB -> latency-serialized: VGPR=72 proves only ~2 of 40 row
// loads in flight; each group eats full ~600cyc latency with 1.5 waves/SIMD
// and nothing to overlap. FMA floor (6.5us) == measured VALUBusy share.
// R13: finalize_v6 keeps node-per-lane + SGPR-folded weights (zero LDS/bcast)
// but hand-pipelines the loads: 8-vf4 groups, load G(i+1) issued before
// FMA G(i) (2 groups = 64 VGPR live), so all but the first exposure hide
// under 2048 FMA cycles. VGPR ~115 -> 4 waves/SIMD.
// place/aggregate unchanged (R8 proven forms).

constexpr int N_NODES  = 50000;
constexpr int N_EDGES  = 800000;
constexpr int IN_DIM   = 64;
constexpr int EDGE_DIM = 32;
constexpr int OUT_DIM  = 64;
constexpr int CAP      = 48;      // bucket capacity; Poisson(16) max deg ~40
constexpr int OVF_CAP  = 65536;   // overflow list capacity (deg>CAP tails)

using vf4 = __attribute__((ext_vector_type(4))) float;
using vi2 = __attribute__((ext_vector_type(2))) int;

// ---------------------------------------------------------------------------
// K1: single-pass bucket build. pos = atomicAdd(cnt[dst]); write (e,src).
// Rare pos>=CAP goes to the overflow list.
// ---------------------------------------------------------------------------
__device__ __forceinline__ void place_one(int dst, int e, int src,
                                          int* cnt, int2* buckets,
                                          int4* ovf, int* ovf_cur) {
    const int pos = atomicAdd(&cnt[dst], 1);
    if (pos < CAP) {
        buckets[(size_t)dst * CAP + pos] = make_int2(e, src);
    } else {
        const int o = atomicAdd(ovf_cur, 1);
        if (o < OVF_CAP) ovf[o] = make_int4(dst, e, src, 0);
    }
}

__global__ __launch_bounds__(256) void place_bucket_k(
    const int* __restrict__ ei, int* cnt, int2* __restrict__ buckets,
    int4* __restrict__ ovf, int* ovf_cur)
{
    const int t = blockIdx.x * 256 + threadIdx.x;
    if (t * 4 + 3 < N_EDGES) {
        const int4 d4 = ((const int4*)(ei + N_EDGES))[t];
        const int4 s4 = ((const int4*)ei)[t];
        place_one(d4.x, 4 * t + 0, s4.x, cnt, buckets, ovf, ovf_cur);
        place_one(d4.y, 4 * t + 1, s4.y, cnt, buckets, ovf, ovf_cur);
        place_one(d4.z, 4 * t + 2, s4.z, cnt, buckets, ovf, ovf_cur);
        place_one(d4.w, 4 * t + 3, s4.w, cnt, buckets, ovf, ovf_cur);
    } else {
        for (int e = t * 4; e < min(t * 4 + 4, N_EDGES); ++e)
            place_one(ei[N_EDGES + e], e, ei[e], cnt, buckets, ovf, ovf_cur);
    }
}

// ---------------------------------------------------------------------------
// K2 (R8 proven form, unchanged): gather-reduce, 2 nodes/wave, 16 edges/iter,
// 12 gathers issued into zero-init masked temps before any accumulate.
// ---------------------------------------------------------------------------
__global__ __launch_bounds__(256) void aggregate_bucket_k(
    const float* __restrict__ x, const float* __restrict__ ea,
    const int2* __restrict__ buckets, const int* __restrict__ cnt,
    const int4* __restrict__ ovf, const int* __restrict__ ovf_cur,
    float* __restrict__ sum_x, float* __restrict__ sum_ea)
{
    const int lane   = threadIdx.x & 63;
    const int wave   = (blockIdx.x * blockDim.x + threadIdx.x) >> 6;
    const int nwaves = (gridDim.x * blockDim.x) >> 6;

    const int grpx = lane >> 4, colx = lane & 15;  // x: 4 edges/step
    const int grpe = lane >> 3, cole = lane & 7;   // ea: 8 edges/step

    for (int n0 = wave * 2; n0 < N_NODES; n0 += nwaves * 2) {
        const int  nA   = __builtin_amdgcn_readfirstlane(n0);
        const bool hasB = (n0 + 1 < N_NODES);
        const int  nB   = nA + 1;

        const int cFA = __builtin_amdgcn_readfirstlane(cnt[nA]);
        const int cFB = hasB ? __builtin_amdgcn_readfirstlane(cnt[nB]) : 0;
        const int cA  = min(cFA, CAP);
        const int cB  = min(cFB, CAP);

        int eA = 0, srcA = 0, eB = 0, srcB = 0;
        if (lane < cA) {
            const vi2 p = __builtin_nontemporal_load(
                (const vi2*)buckets + (size_t)nA * CAP + lane);
            eA = p.x; srcA = p.y;
        }
        if (lane < cB) {
            const vi2 p = __builtin_nontemporal_load(
                (const vi2*)buckets + (size_t)nB * CAP + lane);
            eB = p.x; srcB = p.y;
        }

        vf4 axA = {0,0,0,0}, aeA = {0,0,0,0};
        vf4 axB = {0,0,0,0}, aeB = {0,0,0,0};

        const int mMax = max(cA, cB);
        for (int j = 0; j < mMax; j += 16) {
            const int jx0 = j +  0 + grpx, jx1 = j +  4 + grpx;
            const int jx2 = j +  8 + grpx, jx3 = j + 12 + grpx;
            const int je0 = j +  0 + grpe, je1 = j +  8 + grpe;
            // max shuffled lane index 47 < 64; lanes >= cnt hold 0 -> valid.
            const int sA0 = __shfl(srcA, jx0), sA1 = __shfl(srcA, jx1);
            const int sA2 = __shfl(srcA, jx2), sA3 = __shfl(srcA, jx3);
            const int sB0 = __shfl(srcB, jx0), sB1 = __shfl(srcB, jx1);
            const int sB2 = __shfl(srcB, jx2), sB3 = __shfl(srcB, jx3);
            const int fA0 = __shfl(eA, je0),   fA1 = __shfl(eA, je1);
            const int fB0 = __shfl(eB, je0),   fB1 = __shfl(eB, je1);

            vf4 xA0 = {0,0,0,0}, xA1 = {0,0,0,0}, xA2 = {0,0,0,0}, xA3 = {0,0,0,0};
            vf4 xB0 = {0,0,0,0}, xB1 = {0,0,0,0}, xB2 = {0,0,0,0}, xB3 = {0,0,0,0};
            vf4 eA0v = {0,0,0,0}, eA1v = {0,0,0,0};
            vf4 eB0v = {0,0,0,0}, eB1v = {0,0,0,0};

            // all 12 loads issue before any accumulate (independent temps)
            if (jx0 < cA) xA0 = ((const vf4*)(x + (size_t)sA0 * IN_DIM))[colx];
            if (jx1 < cA) xA1 = ((const vf4*)(x + (size_t)sA1 * IN_DIM))[colx];
            if (jx2 < cA) xA2 = ((const vf4*)(x + (size_t)sA2 * IN_DIM))[colx];
            if (jx3 < cA) xA3 = ((const vf4*)(x + (size_t)sA3 * IN_DIM))[colx];
            if (jx0 < cB) xB0 = ((const vf4*)(x + (size_t)sB0 * IN_DIM))[colx];
            if (jx1 < cB) xB1 = ((const vf4*)(x + (size_t)sB1 * IN_DIM))[colx];
            if (jx2 < cB) xB2 = ((const vf4*)(x + (size_t)sB2 * IN_DIM))[colx];
            if (jx3 < cB) xB3 = ((const vf4*)(x + (size_t)sB3 * IN_DIM))[colx];
            if (je0 < cA) eA0v = __builtin_nontemporal_load(
                (const vf4*)(ea + (size_t)fA0 * EDGE_DIM) + cole);
            if (je1 < cA) eA1v = __builtin_nontemporal_load(
                (const vf4*)(ea + (size_t)fA1 * EDGE_DIM) + cole);
            if (je0 < cB) eB0v = __builtin_nontemporal_load(
                (const vf4*)(ea + (size_t)fB0 * EDGE_DIM) + cole);
            if (je1 < cB) eB1v = __builtin_nontemporal_load(
                (const vf4*)(ea + (size_t)fB1 * EDGE_DIM) + cole);

            axA += (xA0 + xA1) + (xA2 + xA3);
            axB += (xB0 + xB1) + (xB2 + xB3);
            aeA += eA0v + eA1v;
            aeB += eB0v + eB1v;
        }

        // rare: overflow entries (deg > CAP). Group 0 accumulates pre-reduce.
        if (cFA > CAP || cFB > CAP) {
            const int novf = min(__builtin_amdgcn_readfirstlane(*ovf_cur), OVF_CAP);
            for (int i = 0; i < novf; ++i) {
                const int4 v = ovf[i];
                const bool mA = (v.x == nA), mB = hasB && (v.x == nB);
                if (mA || mB) {
                    if (grpx == 0) {
                        const vf4 t = ((const vf4*)(x + (size_t)v.z * IN_DIM))[colx];
                        if (mA) axA += t; else axB += t;
                    }
                    if (grpe == 0) {
                        const vf4 t = ((const vf4*)(ea + (size_t)v.y * EDGE_DIM))[cole];
                        if (mA) aeA += t; else aeB += t;
                    }
                }
            }
        }

#pragma unroll
        for (int mask = 16; mask < 64; mask <<= 1) {
            axA.x += __shfl_xor(axA.x, mask); axA.y += __shfl_xor(axA.y, mask);
            axA.z += __shfl_xor(axA.z, mask); axA.w += __shfl_xor(axA.w, mask);
            axB.x += __shfl_xor(axB.x, mask); axB.y += __shfl_xor(axB.y, mask);
            axB.z += __shfl_xor(axB.z, mask); axB.w += __shfl_xor(axB.w, mask);
        }
#pragma unroll
        for (int mask = 8; mask < 64; mask <<= 1) {
            aeA.x += __shfl_xor(aeA.x, mask); aeA.y += __shfl_xor(aeA.y, mask);
            aeA.z += __shfl_xor(aeA.z, mask); aeA.w += __shfl_xor(aeA.w, mask);
            aeB.x += __shfl_xor(aeB.x, mask); aeB.y += __shfl_xor(aeB.y, mask);
            aeB.z += __shfl_xor(aeB.z, mask); aeB.w += __shfl_xor(aeB.w, mask);
        }

        if (lane < 16) ((vf4*)(sum_x + (size_t)nA * IN_DIM))[lane] = axA;
        if (lane < 8)  ((vf4*)(sum_ea + (size_t)nA * EDGE_DIM))[lane] = aeA;
        if (hasB) {
            if (lane < 16) ((vf4*)(sum_x + (size_t)nB * IN_DIM))[lane] = axB;
            if (lane < 8)  ((vf4*)(sum_ea + (size_t)nB * EDGE_DIM))[lane] = aeB;
        }
    }
}

// ---------------------------------------------------------------------------
// K3 (R13): finalize_v6 — node-per-lane + SGPR weights + hand-pipelined
// 8-vf4 load groups. Wave unit = (64-node block, 32-col half); 1564 units,
// one per wave. Group schedule: load A,B -> FMA A | load C -> FMA B |
// load D -> FMA C(+scale) | load E -> FMA D -> FMA E. Only 2 groups live
// (64 VGPR); every latency but A's hides under 2048 FMA-issue cycles.
// ---------------------------------------------------------------------------
__global__ __launch_bounds__(256) void finalize_v6_k(
    const float* __restrict__ x, const float* __restrict__ sum_x_in,
    const float* __restrict__ sum_ea, const int* __restrict__ cnt,
    const float* __restrict__ msg_w, const float* __restrict__ msg_b,
    const float* __restrict__ self_w, const float* __restrict__ self_b,
    float* __restrict__ out)
{
    const int lane   = threadIdx.x & 63;
    const int wunit  = blockIdx.x * 4 + (threadIdx.x >> 6);  // 0..1563
    const int rowblk = wunit >> 1;
    const int c0     = (wunit & 1) << 5;                     // 0 or 32
    const int n      = rowblk * 64 + lane;
    const bool live  = (n < N_NODES);
    const int  nn    = live ? n : 0;   // clamp: safe loads, store masked

    const vf4* rx = (const vf4*)(sum_x_in + (size_t)nn * IN_DIM);
    const vf4* re = (const vf4*)(sum_ea   + (size_t)nn * EDGE_DIM);
    const vf4* rs = (const vf4*)(x        + (size_t)nn * IN_DIM);

    float acc[32];
#pragma unroll
    for (int c = 0; c < 32; ++c) acc[c] = 0.f;

    // one FMA group: 8 vf4 (32 k-values) against W rows kbase..kbase+31
    auto fmag = [&](const vf4* g, int kbase, const float* W) {
#pragma unroll
        for (int j = 0; j < 8; ++j)
#pragma unroll
            for (int i = 0; i < 4; ++i) {
                const float  vi   = g[j][i];
                const float* wrow = W + (size_t)(kbase + 4 * j + i) * OUT_DIM + c0;
#pragma unroll
                for (int c = 0; c < 32; ++c)
                    acc[c] = fmaf(vi, wrow[c], acc[c]);  // wrow[c] uniform->SGPR
            }
    };

    vf4 ga[8], gb[8];
    const int d = cnt[nn];
#pragma unroll
    for (int j = 0; j < 8; ++j) ga[j] = rx[j];        // A: sum_x[0:32]
#pragma unroll
    for (int j = 0; j < 8; ++j) gb[j] = rx[8 + j];    // B: sum_x[32:64]

    fmag(ga, 0, msg_w);                               // FMA A  (C loads below)
#pragma unroll
    for (int j = 0; j < 8; ++j) ga[j] = re[j];        // C: sum_ea[0:32]
    fmag(gb, 32, msg_w);                              // FMA B
#pragma unroll
    for (int j = 0; j < 8; ++j) gb[j] = rs[j];        // D: x[0:32]
    fmag(ga, 64, msg_w);                              // FMA C

    // msg part done: mean + msg bias (bias only when deg>0)
    const float inv  = 1.0f / (float)max(d, 1);
    const float bsel = (d > 0) ? 1.0f : 0.0f;
#pragma unroll
    for (int c = 0; c < 32; ++c)
        acc[c] = fmaf(acc[c], inv, msg_b[c0 + c] * bsel);

#pragma unroll
    for (int j = 0; j < 8; ++j) ga[j] = rs[8 + j];    // E: x[32:64]
    fmag(gb, 0, self_w);                              // FMA D
    fmag(ga, 32, self_w);                             // FMA E

#pragma unroll
    for (int c = 0; c < 32; ++c) acc[c] += self_b[c0 + c];

    if (live) {
        float* op = out + (size_t)n * OUT_DIM + c0;
#pragma unroll
        for (int qq = 0; qq < 8; ++qq)
            ((vf4*)op)[qq] = (vf4){acc[4 * qq + 0], acc[4 * qq + 1],
                                   acc[4 * qq + 2], acc[4 * qq + 3]};
    }
}

// ---------------------------------------------------------------------------
// Tier-3 fallback: atomic scatter (needs only ~19.4 MB ws).
// ---------------------------------------------------------------------------
__global__ __launch_bounds__(768) void scatter_fb_k(
    const float* __restrict__ x, const int* __restrict__ ei,
    const float* __restrict__ ea, float* sum_x, float* sum_ea, int* deg)
{
    const int t  = threadIdx.x;
    const int el = t / 96;
    const int k  = t - el * 96;
    const int e  = blockIdx.x * 8 + el;
    if (e >= N_EDGES) return;
    const int dst = ei[N_EDGES + e];
    if (k < IN_DIM) {
        const int src = ei[e];
        atomicAdd(&sum_x[dst * IN_DIM + k], x[src * IN_DIM + k]);
        if (k == 0) atomicAdd(&deg[dst], 1);
    } else {
        const int kk = k - IN_DIM;
        atomicAdd(&sum_ea[dst * EDGE_DIM + kk], ea[e * EDGE_DIM + kk]);
    }
}

// ---------------------------------------------------------------------------
extern "C" void kernel_launch(void* const* d_in, const int* in_sizes, int n_in,
                              void* d_out, int out_size, void* d_ws, size_t ws_size,
                              hipStream_t stream) {
    const float* x      = (const float*)d_in[0];
    const int*   ei     = (const int*)d_in[1];   // [2][E]
    const float* ea     = (const float*)d_in[2];
    const float* msg_w  = (const float*)d_in[3];
    const float* msg_b  = (const float*)d_in[4];
    const float* self_w = (const float*)d_in[5];
    const float* self_b = (const float*)d_in[6];

    float* out = (float*)d_out;

    // ws layout (ints unless noted):
    //   cnt[50000] | ovf_cur[1] | pad to 16 | buckets[50000*CAP int2]
    //   | ovf[OVF_CAP int4] | sum_ea[1.6M float] | sum_x[3.2M float]
    int*   cnt     = (int*)d_ws;
    int*   ovf_cur = cnt + N_NODES;
    int2*  buckets = (int2*)(cnt + N_NODES + 16);
    int4*  ovf     = (int4*)(buckets + (size_t)N_NODES * CAP);
    float* sum_ea  = (float*)(ovf + OVF_CAP);
    float* sum_x   = sum_ea + (size_t)N_NODES * EDGE_DIM;
    const size_t need_bucket =
        ((size_t)N_NODES + 16 + 2 * (size_t)N_NODES * CAP + 4 * (size_t)OVF_CAP +
         (size_t)N_NODES * EDGE_DIM + (size_t)N_NODES * IN_DIM) * sizeof(int);

    constexpr int FIN_BLOCKS = ((N_NODES + 63) / 64 * 2 + 3) / 4;  // 391

    if (ws_size >= need_bucket) {
        hipMemsetAsync(cnt, 0, (N_NODES + 16) * sizeof(int), stream);
        place_bucket_k<<<(N_EDGES / 4 + 255) / 256, 256, 0, stream>>>(
            ei, cnt, buckets, ovf, ovf_cur);
        aggregate_bucket_k<<<(N_NODES / 2 + 3) / 4, 256, 0, stream>>>(
            x, ea, buckets, cnt, ovf, ovf_cur, sum_x, sum_ea);
        finalize_v6_k<<<FIN_BLOCKS, 256, 0, stream>>>(
            x, sum_x, sum_ea, cnt, msg_w, msg_b, self_w, self_b, out);
    } else {
        // Fallback: fp32 atomic scatter (R1 path) + finalize_v6
        float* fb_sum_x  = (float*)d_ws;
        float* fb_sum_ea = fb_sum_x + (size_t)N_NODES * IN_DIM;
        int*   deg       = (int*)(fb_sum_ea + (size_t)N_NODES * EDGE_DIM);
        hipMemsetAsync(d_ws, 0,
                       (size_t)N_NODES * (IN_DIM + EDGE_DIM + 1) * sizeof(float),
                       stream);
        scatter_fb_k<<<(N_EDGES + 7) / 8, 768, 0, stream>>>(
            x, ei, ea, fb_sum_x, fb_sum_ea, deg);
        finalize_v6_k<<<FIN_BLOCKS, 256, 0, stream>>>(
            x, fb_sum_x, fb_sum_ea, deg, msg_w, msg_b, self_w, self_b, out);
    }
}

// Round 7
// 277.763 us; speedup vs baseline: 1.1964x; 1.1964x over previous
//
#include <hip/hip_runtime.h>

// EdgeSageLayer on MI355X — round 14.
// agg[n] = (sum_{e:dst=n} concat(x[src_e], ea_e)) @ msg_w / deg + msg_b*(deg>0)
// R13 postmortem: finalize_v6 96us: "SGPR weights" compiled to ~640 s_load/wave
// (K$ thrash, ~300cyc each, serialized == measured 230K cyc/wave). All VALU
// finalize forms are issue-bound >=26us (one instr per input-broadcast).
// R14: the broadcast engine is the MATRIX CORE. bf16-SPLIT GEMM finalize:
// v = hi + lo (two bf16 planes, ~17 mantissa bits); D = Ah*Wh + Al*Wh + Ah*Wl
// (err ~1e-4 << passing 0.0156). Aggregate epilogue pre-scales by 1/deg and
// emits the hi/lo planes (same bytes as fp32). place kernel tail-blocks split
// x into planes at k=96..159. finalize: W swizzled to B-frag order in LDS
// (40KB), 1 wave = 16 nodes x 64 cols = 10 A-frag loads + 40 ds_read_b128 +
// 60 mfma_f32_16x16x32_bf16. Layouts: A row=lane&15,k=(lane>>4)*8+j;
// C/D col=lane&15,row=(lane>>4)*4+reg (m89-verified).

constexpr int N_NODES  = 50000;
constexpr int N_EDGES  = 800000;
constexpr int IN_DIM   = 64;
constexpr int EDGE_DIM = 32;
constexpr int OUT_DIM  = 64;
constexpr int K_CAT    = 160;     // 64 sum_x + 32 sum_ea + 64 x
constexpr int CAP      = 48;      // bucket capacity; Poisson(16) max deg ~40
constexpr int OVF_CAP  = 65536;   // overflow list capacity (deg>CAP tails)

using vf4   = __attribute__((ext_vector_type(4))) float;
using vi2   = __attribute__((ext_vector_type(2))) int;
using vu4   = __attribute__((ext_vector_type(4))) unsigned short;
using bf8   = __attribute__((ext_vector_type(8))) short;   // 8 bf16 (4 VGPR)
using f32x4 = __attribute__((ext_vector_type(4))) float;

__device__ __forceinline__ unsigned short f2bf(float f) {   // RNE
    unsigned int u = __float_as_uint(f);
    return (unsigned short)((u + 0x7fffu + ((u >> 16) & 1u)) >> 16);
}
__device__ __forceinline__ float bf2f(unsigned short h) {
    return __uint_as_float(((unsigned int)h) << 16);
}

// ---------------------------------------------------------------------------
// K1: single-pass bucket build (blocks < PLACE_BLOCKS) + x bf16-split
// (tail blocks). place: pos = atomicAdd(cnt[dst]); write (e,src); rare
// pos>=CAP goes to the overflow list. xsplit: planes ch/cl at k=96..159.
// ---------------------------------------------------------------------------
constexpr int PLACE_BLOCKS  = (N_EDGES / 4 + 255) / 256;  // 782
constexpr int XSPLIT_BLOCKS = 200;

__device__ __forceinline__ void place_one(int dst, int e, int src,
                                          int* cnt, int2* buckets,
                                          int4* ovf, int* ovf_cur) {
    const int pos = atomicAdd(&cnt[dst], 1);
    if (pos < CAP) {
        buckets[(size_t)dst * CAP + pos] = make_int2(e, src);
    } else {
        const int o = atomicAdd(ovf_cur, 1);
        if (o < OVF_CAP) ovf[o] = make_int4(dst, e, src, 0);
    }
}

__global__ __launch_bounds__(256) void place_xsplit_k(
    const int* __restrict__ ei, int* cnt, int2* __restrict__ buckets,
    int4* __restrict__ ovf, int* ovf_cur,
    const float* __restrict__ x, unsigned short* __restrict__ ch,
    unsigned short* __restrict__ cl)
{
    if (blockIdx.x < PLACE_BLOCKS) {
        const int t = blockIdx.x * 256 + threadIdx.x;
        if (t * 4 + 3 < N_EDGES) {
            const int4 d4 = ((const int4*)(ei + N_EDGES))[t];
            const int4 s4 = ((const int4*)ei)[t];
            place_one(d4.x, 4 * t + 0, s4.x, cnt, buckets, ovf, ovf_cur);
            place_one(d4.y, 4 * t + 1, s4.y, cnt, buckets, ovf, ovf_cur);
            place_one(d4.z, 4 * t + 2, s4.z, cnt, buckets, ovf, ovf_cur);
            place_one(d4.w, 4 * t + 3, s4.w, cnt, buckets, ovf, ovf_cur);
        } else {
            for (int e = t * 4; e < min(t * 4 + 4, N_EDGES); ++e)
                place_one(ei[N_EDGES + e], e, ei[e], cnt, buckets, ovf, ovf_cur);
        }
    } else {
        // x split: quad i = (node n, 4 elems at 4q). 800000 quads.
        const int base   = (blockIdx.x - PLACE_BLOCKS) * 256 + threadIdx.x;
        const int stride = XSPLIT_BLOCKS * 256;
        for (int i = base; i < N_NODES * 16; i += stride) {
            const vf4 v = ((const vf4*)x)[i];
            const int n = i >> 4, q = i & 15;
            vu4 h, l;
#pragma unroll
            for (int j = 0; j < 4; ++j) {
                h[j] = f2bf(v[j]);
                l[j] = f2bf(v[j] - bf2f(h[j]));
            }
            const size_t o = (size_t)n * K_CAT + 96 + 4 * q;
            *(vu4*)(ch + o) = h;
            *(vu4*)(cl + o) = l;
        }
    }
}

// ---------------------------------------------------------------------------
// K2 (R8 proven gather, new epilogue): 2 nodes/wave, 16 edges/iter, 12
// gathers in flight. Epilogue pre-scales sums by 1/deg and stores bf16
// hi/lo planes at k=0..95 (same byte count as fp32; cvt hidden by latency).
// ---------------------------------------------------------------------------
__global__ __launch_bounds__(256) void aggregate_bucket_k(
    const float* __restrict__ x, const float* __restrict__ ea,
    const int2* __restrict__ buckets, const int* __restrict__ cnt,
    const int4* __restrict__ ovf, const int* __restrict__ ovf_cur,
    unsigned short* __restrict__ ch, unsigned short* __restrict__ cl)
{
    const int lane   = threadIdx.x & 63;
    const int wave   = (blockIdx.x * blockDim.x + threadIdx.x) >> 6;
    const int nwaves = (gridDim.x * blockDim.x) >> 6;

    const int grpx = lane >> 4, colx = lane & 15;  // x: 4 edges/step
    const int grpe = lane >> 3, cole = lane & 7;   // ea: 8 edges/step

    for (int n0 = wave * 2; n0 < N_NODES; n0 += nwaves * 2) {
        const int  nA   = __builtin_amdgcn_readfirstlane(n0);
        const bool hasB = (n0 + 1 < N_NODES);
        const int  nB   = nA + 1;

        const int cFA = __builtin_amdgcn_readfirstlane(cnt[nA]);
        const int cFB = hasB ? __builtin_amdgcn_readfirstlane(cnt[nB]) : 0;
        const int cA  = min(cFA, CAP);
        const int cB  = min(cFB, CAP);

        int eA = 0, srcA = 0, eB = 0, srcB = 0;
        if (lane < cA) {
            const vi2 p = __builtin_nontemporal_load(
                (const vi2*)buckets + (size_t)nA * CAP + lane);
            eA = p.x; srcA = p.y;
        }
        if (lane < cB) {
            const vi2 p = __builtin_nontemporal_load(
                (const vi2*)buckets + (size_t)nB * CAP + lane);
            eB = p.x; srcB = p.y;
        }

        vf4 axA = {0,0,0,0}, aeA = {0,0,0,0};
        vf4 axB = {0,0,0,0}, aeB = {0,0,0,0};

        const int mMax = max(cA, cB);
        for (int j = 0; j < mMax; j += 16) {
            const int jx0 = j +  0 + grpx, jx1 = j +  4 + grpx;
            const int jx2 = j +  8 + grpx, jx3 = j + 12 + grpx;
            const int je0 = j +  0 + grpe, je1 = j +  8 + grpe;
            const int sA0 = __shfl(srcA, jx0), sA1 = __shfl(srcA, jx1);
            const int sA2 = __shfl(srcA, jx2), sA3 = __shfl(srcA, jx3);
            const int sB0 = __shfl(srcB, jx0), sB1 = __shfl(srcB, jx1);
            const int sB2 = __shfl(srcB, jx2), sB3 = __shfl(srcB, jx3);
            const int fA0 = __shfl(eA, je0),   fA1 = __shfl(eA, je1);
            const int fB0 = __shfl(eB, je0),   fB1 = __shfl(eB, je1);

            vf4 xA0 = {0,0,0,0}, xA1 = {0,0,0,0}, xA2 = {0,0,0,0}, xA3 = {0,0,0,0};
            vf4 xB0 = {0,0,0,0}, xB1 = {0,0,0,0}, xB2 = {0,0,0,0}, xB3 = {0,0,0,0};
            vf4 eA0v = {0,0,0,0}, eA1v = {0,0,0,0};
            vf4 eB0v = {0,0,0,0}, eB1v = {0,0,0,0};

            if (jx0 < cA) xA0 = ((const vf4*)(x + (size_t)sA0 * IN_DIM))[colx];
            if (jx1 < cA) xA1 = ((const vf4*)(x + (size_t)sA1 * IN_DIM))[colx];
            if (jx2 < cA) xA2 = ((const vf4*)(x + (size_t)sA2 * IN_DIM))[colx];
            if (jx3 < cA) xA3 = ((const vf4*)(x + (size_t)sA3 * IN_DIM))[colx];
            if (jx0 < cB) xB0 = ((const vf4*)(x + (size_t)sB0 * IN_DIM))[colx];
            if (jx1 < cB) xB1 = ((const vf4*)(x + (size_t)sB1 * IN_DIM))[colx];
            if (jx2 < cB) xB2 = ((const vf4*)(x + (size_t)sB2 * IN_DIM))[colx];
            if (jx3 < cB) xB3 = ((const vf4*)(x + (size_t)sB3 * IN_DIM))[colx];
            if (je0 < cA) eA0v = __builtin_nontemporal_load(
                (const vf4*)(ea + (size_t)fA0 * EDGE_DIM) + cole);
            if (je1 < cA) eA1v = __builtin_nontemporal_load(
                (const vf4*)(ea + (size_t)fA1 * EDGE_DIM) + cole);
            if (je0 < cB) eB0v = __builtin_nontemporal_load(
                (const vf4*)(ea + (size_t)fB0 * EDGE_DIM) + cole);
            if (je1 < cB) eB1v = __builtin_nontemporal_load(
                (const vf4*)(ea + (size_t)fB1 * EDGE_DIM) + cole);

            axA += (xA0 + xA1) + (xA2 + xA3);
            axB += (xB0 + xB1) + (xB2 + xB3);
            aeA += eA0v + eA1v;
            aeB += eB0v + eB1v;
        }

        if (cFA > CAP || cFB > CAP) {
            const int novf = min(__builtin_amdgcn_readfirstlane(*ovf_cur), OVF_CAP);
            for (int i = 0; i < novf; ++i) {
                const int4 v = ovf[i];
                const bool mA = (v.x == nA), mB = hasB && (v.x == nB);
                if (mA || mB) {
                    if (grpx == 0) {
                        const vf4 t = ((const vf4*)(x + (size_t)v.z * IN_DIM))[colx];
                        if (mA) axA += t; else axB += t;
                    }
                    if (grpe == 0) {
                        const vf4 t = ((const vf4*)(ea + (size_t)v.y * EDGE_DIM))[cole];
                        if (mA) aeA += t; else aeB += t;
                    }
                }
            }
        }

#pragma unroll
        for (int mask = 16; mask < 64; mask <<= 1) {
            axA.x += __shfl_xor(axA.x, mask); axA.y += __shfl_xor(axA.y, mask);
            axA.z += __shfl_xor(axA.z, mask); axA.w += __shfl_xor(axA.w, mask);
            axB.x += __shfl_xor(axB.x, mask); axB.y += __shfl_xor(axB.y, mask);
            axB.z += __shfl_xor(axB.z, mask); axB.w += __shfl_xor(axB.w, mask);
        }
#pragma unroll
        for (int mask = 8; mask < 64; mask <<= 1) {
            aeA.x += __shfl_xor(aeA.x, mask); aeA.y += __shfl_xor(aeA.y, mask);
            aeA.z += __shfl_xor(aeA.z, mask); aeA.w += __shfl_xor(aeA.w, mask);
            aeB.x += __shfl_xor(aeB.x, mask); aeB.y += __shfl_xor(aeB.y, mask);
            aeB.z += __shfl_xor(aeB.z, mask); aeB.w += __shfl_xor(aeB.w, mask);
        }

        // epilogue: pre-scale by 1/deg, bf16-split, store hi/lo planes.
        const float invA = 1.0f / (float)max(cFA, 1);
        const float invB = 1.0f / (float)max(cFB, 1);
        {
            unsigned short* rhA = ch + (size_t)nA * K_CAT;
            unsigned short* rlA = cl + (size_t)nA * K_CAT;
            if (lane < 16) {
                vu4 h, l;
#pragma unroll
                for (int j = 0; j < 4; ++j) {
                    const float v = axA[j] * invA;
                    h[j] = f2bf(v); l[j] = f2bf(v - bf2f(h[j]));
                }
                *(vu4*)(rhA + 4 * lane) = h;
                *(vu4*)(rlA + 4 * lane) = l;
            }
            if (lane < 8) {
                vu4 h, l;
#pragma unroll
                for (int j = 0; j < 4; ++j) {
                    const float v = aeA[j] * invA;
                    h[j] = f2bf(v); l[j] = f2bf(v - bf2f(h[j]));
                }
                *(vu4*)(rhA + 64 + 4 * lane) = h;
                *(vu4*)(rlA + 64 + 4 * lane) = l;
            }
        }
        if (hasB) {
            unsigned short* rhB = ch + (size_t)nB * K_CAT;
            unsigned short* rlB = cl + (size_t)nB * K_CAT;
            if (lane < 16) {
                vu4 h, l;
#pragma unroll
                for (int j = 0; j < 4; ++j) {
                    const float v = axB[j] * invB;
                    h[j] = f2bf(v); l[j] = f2bf(v - bf2f(h[j]));
                }
                *(vu4*)(rhB + 4 * lane) = h;
                *(vu4*)(rlB + 4 * lane) = l;
            }
            if (lane < 8) {
                vu4 h, l;
#pragma unroll
                for (int j = 0; j < 4; ++j) {
                    const float v = aeB[j] * invB;
                    h[j] = f2bf(v); l[j] = f2bf(v - bf2f(h[j]));
                }
                *(vu4*)(rhB + 64 + 4 * lane) = h;
                *(vu4*)(rlB + 64 + 4 * lane) = l;
            }
        }
    }
}

// ---------------------------------------------------------------------------
// K3 (R14): MFMA finalize. out = concat_planes @ [msg_w; self_w] + biases.
// Per block: swizzle W (hi+lo) into B-fragment order in LDS (40 KB).
// Per wave: one 16-node tile x 64 cols; A-frags ah/al[5] (16B/lane loads);
// acc[ct] += mfma(ah,bh) + mfma(al,bh) + mfma(ah,bl) over 5 k-tiles.
// Epilogue: + msg_b*(deg>0) + self_b (1/deg already folded into planes).
// ---------------------------------------------------------------------------
__global__ __launch_bounds__(256) void finalize_mfma_k(
    const unsigned short* __restrict__ ch, const unsigned short* __restrict__ cl,
    const int* __restrict__ cnt,
    const float* __restrict__ msg_w, const float* __restrict__ msg_b,
    const float* __restrict__ self_w, const float* __restrict__ self_b,
    float* __restrict__ out)
{
    __shared__ short wfh[1280 * 8];  // [ (ct*5+kt)*64 + lane ][8] hi plane
    __shared__ short wfl[1280 * 8];  // lo plane

    const int tid  = threadIdx.x;
    const int lane = tid & 63;

    // W swizzle: entry (ct,kt,l) holds B-frag: k=kt*32+(l>>4)*8+j, c=ct*16+(l&15)
    for (int idx = tid; idx < 1280; idx += 256) {
        const int ct = idx / 320, rem = idx % 320;
        const int kt = rem / 64,  l   = rem % 64;
        const int c  = ct * 16 + (l & 15);
        const int k0 = kt * 32 + ((l >> 4) << 3);
#pragma unroll
        for (int j = 0; j < 8; ++j) {
            const int k = k0 + j;
            const float w = (k < 96) ? msg_w[k * OUT_DIM + c]
                                     : self_w[(k - 96) * OUT_DIM + c];
            const unsigned short h = f2bf(w);
            wfh[idx * 8 + j] = (short)h;
            wfl[idx * 8 + j] = (short)f2bf(w - bf2f(h));
        }
    }
    __syncthreads();

    // per-lane bias values for each col-tile
    float mbv[4], sbv[4];
#pragma unroll
    for (int ct = 0; ct < 4; ++ct) {
        mbv[ct] = msg_b[ct * 16 + (lane & 15)];
        sbv[ct] = self_b[ct * 16 + (lane & 15)];
    }

    const int wid = blockIdx.x * 4 + (tid >> 6);
    const int nw  = gridDim.x * 4;

    for (int t = wid; t < N_NODES / 16; t += nw) {
        const int n0 = t * 16;
        // A-fragments: row = n0 + (lane&15), k = kt*32 + (lane>>4)*8 + j
        const size_t abase = (size_t)(n0 + (lane & 15)) * K_CAT + ((lane >> 4) << 3);
        bf8 ah[5], al[5];
#pragma unroll
        for (int kt = 0; kt < 5; ++kt) {
            ah[kt] = *(const bf8*)(ch + abase + kt * 32);
            al[kt] = *(const bf8*)(cl + abase + kt * 32);
        }
        // deg per output row (for msg_b gating): row = n0+(lane>>4)*4+r
        int dr[4];
#pragma unroll
        for (int r = 0; r < 4; ++r)
            dr[r] = cnt[n0 + ((lane >> 4) << 2) + r];

        f32x4 acc[4] = {{0,0,0,0},{0,0,0,0},{0,0,0,0},{0,0,0,0}};
#pragma unroll
        for (int kt = 0; kt < 5; ++kt) {
#pragma unroll
            for (int ct = 0; ct < 4; ++ct) {
                const int e = ((ct * 5 + kt) * 64 + lane) * 8;
                const bf8 bh = *(const bf8*)(wfh + e);
                const bf8 bl = *(const bf8*)(wfl + e);
                acc[ct] = __builtin_amdgcn_mfma_f32_16x16x32_bf16(
                    ah[kt], bh, acc[ct], 0, 0, 0);
                acc[ct] = __builtin_amdgcn_mfma_f32_16x16x32_bf16(
                    al[kt], bh, acc[ct], 0, 0, 0);
                acc[ct] = __builtin_amdgcn_mfma_f32_16x16x32_bf16(
                    ah[kt], bl, acc[ct], 0, 0, 0);
            }
        }

        // store: C/D col=lane&15, row=(lane>>4)*4+r
#pragma unroll
        for (int ct = 0; ct < 4; ++ct) {
#pragma unroll
            for (int r = 0; r < 4; ++r) {
                const float bsel = (dr[r] > 0) ? 1.0f : 0.0f;
                const int   row  = n0 + ((lane >> 4) << 2) + r;
                out[(size_t)row * OUT_DIM + ct * 16 + (lane & 15)] =
                    acc[ct][r] + mbv[ct] * bsel + sbv[ct];
            }
        }
    }
}

// ---------------------------------------------------------------------------
// Fallback path (small ws): atomic scatter + fp32 finalize (R7 proven).
// ---------------------------------------------------------------------------
__global__ __launch_bounds__(768) void scatter_fb_k(
    const float* __restrict__ x, const int* __restrict__ ei,
    const float* __restrict__ ea, float* sum_x, float* sum_ea, int* deg)
{
    const int t  = threadIdx.x;
    const int el = t / 96;
    const int k  = t - el * 96;
    const int e  = blockIdx.x * 8 + el;
    if (e >= N_EDGES) return;
    const int dst = ei[N_EDGES + e];
    if (k < IN_DIM) {
        const int src = ei[e];
        atomicAdd(&sum_x[dst * IN_DIM + k], x[src * IN_DIM + k]);
        if (k == 0) atomicAdd(&deg[dst], 1);
    } else {
        const int kk = k - IN_DIM;
        atomicAdd(&sum_ea[dst * EDGE_DIM + kk], ea[e * EDGE_DIM + kk]);
    }
}

__global__ __launch_bounds__(64) void finalize64_k(
    const float* __restrict__ x, const float* sum_x_in,
    const float* __restrict__ sum_ea, const int* __restrict__ cnt,
    const float* __restrict__ msg_w, const float* __restrict__ msg_b,
    const float* __restrict__ self_w, const float* __restrict__ self_b,
    float* out)
{
    const int c = threadIdx.x;
    float wm[96], wsf[64];
#pragma unroll
    for (int k = 0; k < 96; ++k) wm[k] = msg_w[k * OUT_DIM + c];
#pragma unroll
    for (int k = 0; k < 64; ++k) wsf[k] = self_w[k * OUT_DIM + c];
    const float mb = msg_b[c];
    const float sb = self_b[c];

    for (int n0 = blockIdx.x; n0 < N_NODES; n0 += gridDim.x) {
        const int n = __builtin_amdgcn_readfirstlane(n0);
        const float4* r1 = (const float4*)(sum_x_in + (size_t)n * IN_DIM);
        const float4* r2 = (const float4*)(sum_ea   + (size_t)n * EDGE_DIM);
        const float4* r3 = (const float4*)(x        + (size_t)n * IN_DIM);
        const int d = cnt[n];
        float am0 = 0.f, am1 = 0.f, am2 = 0.f, am3 = 0.f;
        float as0 = 0.f, as1 = 0.f, as2 = 0.f, as3 = 0.f;
#pragma unroll
        for (int q = 0; q < 16; ++q) {
            const float4 v = r1[q];
            am0 = fmaf(v.x, wm[4 * q + 0], am0);
            am1 = fmaf(v.y, wm[4 * q + 1], am1);
            am2 = fmaf(v.z, wm[4 * q + 2], am2);
            am3 = fmaf(v.w, wm[4 * q + 3], am3);
        }
#pragma unroll
        for (int q = 0; q < 8; ++q) {
            const float4 v = r2[q];
            am0 = fmaf(v.x, wm[64 + 4 * q + 0], am0);
            am1 = fmaf(v.y, wm[64 + 4 * q + 1], am1);
            am2 = fmaf(v.z, wm[64 + 4 * q + 2], am2);
            am3 = fmaf(v.w, wm[64 + 4 * q + 3], am3);
        }
#pragma unroll
        for (int q = 0; q < 16; ++q) {
            const float4 v = r3[q];
            as0 = fmaf(v.x, wsf[4 * q + 0], as0);
            as1 = fmaf(v.y, wsf[4 * q + 1], as1);
            as2 = fmaf(v.z, wsf[4 * q + 2], as2);
            as3 = fmaf(v.w, wsf[4 * q + 3], as3);
        }
        const float inv  = 1.0f / (float)max(d, 1);
        const float bsel = (d > 0) ? 1.0f : 0.0f;
        out[(size_t)n * OUT_DIM + c] =
            ((as0 + as1) + (as2 + as3)) + sb +
            ((am0 + am1) + (am2 + am3)) * inv + mb * bsel;
    }
}

// ---------------------------------------------------------------------------
extern "C" void kernel_launch(void* const* d_in, const int* in_sizes, int n_in,
                              void* d_out, int out_size, void* d_ws, size_t ws_size,
                              hipStream_t stream) {
    const float* x      = (const float*)d_in[0];
    const int*   ei     = (const int*)d_in[1];   // [2][E]
    const float* ea     = (const float*)d_in[2];
    const float* msg_w  = (const float*)d_in[3];
    const float* msg_b  = (const float*)d_in[4];
    const float* self_w = (const float*)d_in[5];
    const float* self_b = (const float*)d_in[6];

    float* out = (float*)d_out;

    // ws layout:
    //   cnt[50000] int | ovf_cur[1] | pad16 | buckets[50000*CAP int2]
    //   | ovf[OVF_CAP int4] | ch[50000*160 ushort] | cl[50000*160 ushort]
    int*            cnt     = (int*)d_ws;
    int*            ovf_cur = cnt + N_NODES;
    int2*           buckets = (int2*)(cnt + N_NODES + 16);
    int4*           ovf     = (int4*)(buckets + (size_t)N_NODES * CAP);
    unsigned short* ch      = (unsigned short*)(ovf + OVF_CAP);
    unsigned short* cl      = ch + (size_t)N_NODES * K_CAT;
    const size_t need_bucket =
        ((size_t)N_NODES + 16 + 2 * (size_t)N_NODES * CAP + 4 * (size_t)OVF_CAP) *
            sizeof(int) +
        2 * (size_t)N_NODES * K_CAT * sizeof(unsigned short);

    if (ws_size >= need_bucket) {
        hipMemsetAsync(cnt, 0, (N_NODES + 16) * sizeof(int), stream);
        place_xsplit_k<<<PLACE_BLOCKS + XSPLIT_BLOCKS, 256, 0, stream>>>(
            ei, cnt, buckets, ovf, ovf_cur, x, ch, cl);
        aggregate_bucket_k<<<(N_NODES / 2 + 3) / 4, 256, 0, stream>>>(
            x, ea, buckets, cnt, ovf, ovf_cur, ch, cl);
        finalize_mfma_k<<<(N_NODES / 16 + 3) / 4, 256, 0, stream>>>(
            ch, cl, cnt, msg_w, msg_b, self_w, self_b, out);
    } else {
        // Fallback: fp32 atomic scatter + fp32 finalize
        float* fb_sum_x  = (float*)d_ws;
        float* fb_sum_ea = fb_sum_x + (size_t)N_NODES * IN_DIM;
        int*   deg       = (int*)(fb_sum_ea + (size_t)N_NODES * EDGE_DIM);
        hipMemsetAsync(d_ws, 0,
                       (size_t)N_NODES * (IN_DIM + EDGE_DIM + 1) * sizeof(float),
                       stream);
        scatter_fb_k<<<(N_EDGES + 7) / 8, 768, 0, stream>>>(
            x, ei, ea, fb_sum_x, fb_sum_ea, deg);
        finalize64_k<<<4096, 64, 0, stream>>>(
            x, fb_sum_x, fb_sum_ea, deg, msg_w, msg_b, self_w, self_b, out);
    }
}

// Round 8
// 261.213 us; speedup vs baseline: 1.2722x; 1.0634x over previous
//
#include <hip/hip_runtime.h>

// EdgeSageLayer on MI355X — round 15.
// agg[n] = (sum_{e:dst=n} concat(x[src_e], ea_e)) @ msg_w / deg + msg_b*(deg>0)
// R14 postmortem: MFMA finalize WORKS (~10us, absmax unchanged). But fusing
// the x bf16-split into place regressed place 60->90us: WRITE_SIZE 63.8MB vs
// ~20MB of data == ~1 L2 eviction PER bucket write — the 25.6MB xsplit stream
// evicts partially-filled bucket lines before they coalesce (write-allocate
// churn), stalling the latency-bound atomic path.
// R15: place reverts to PURE bucket build (proven <=60us). The x hi/lo split
// moves into the aggregate EPILOGUE (latency-bound, 90% idle VALU): x[n] row
// hoisted to loop-top (issues with bucket loads, fully hidden), converted and
// stored at k=96..159 beside the existing k=0..95 plane stores.
// Pipeline: place (atomics) | aggregate (gather+reduce -> bf16 planes, /deg
// folded) | finalize (bf16-split MFMA: D = Ah*Wh + Al*Wh + Ah*Wl).

constexpr int N_NODES  = 50000;
constexpr int N_EDGES  = 800000;
constexpr int IN_DIM   = 64;
constexpr int EDGE_DIM = 32;
constexpr int OUT_DIM  = 64;
constexpr int K_CAT    = 160;     // 64 sum_x + 32 sum_ea + 64 x
constexpr int CAP      = 48;      // bucket capacity; Poisson(16) max deg ~40
constexpr int OVF_CAP  = 65536;   // overflow list capacity (deg>CAP tails)

using vf4   = __attribute__((ext_vector_type(4))) float;
using vi2   = __attribute__((ext_vector_type(2))) int;
using vu4   = __attribute__((ext_vector_type(4))) unsigned short;
using bf8   = __attribute__((ext_vector_type(8))) short;   // 8 bf16 (4 VGPR)
using f32x4 = __attribute__((ext_vector_type(4))) float;

__device__ __forceinline__ unsigned short f2bf(float f) {   // RNE
    unsigned int u = __float_as_uint(f);
    return (unsigned short)((u + 0x7fffu + ((u >> 16) & 1u)) >> 16);
}
__device__ __forceinline__ float bf2f(unsigned short h) {
    return __uint_as_float(((unsigned int)h) << 16);
}

// ---------------------------------------------------------------------------
// K1 (pure, R8-proven): single-pass bucket build. pos = atomicAdd(cnt[dst]);
// write (e,src). Rare pos>=CAP goes to the overflow list.
// ---------------------------------------------------------------------------
__device__ __forceinline__ void place_one(int dst, int e, int src,
                                          int* cnt, int2* buckets,
                                          int4* ovf, int* ovf_cur) {
    const int pos = atomicAdd(&cnt[dst], 1);
    if (pos < CAP) {
        buckets[(size_t)dst * CAP + pos] = make_int2(e, src);
    } else {
        const int o = atomicAdd(ovf_cur, 1);
        if (o < OVF_CAP) ovf[o] = make_int4(dst, e, src, 0);
    }
}

__global__ __launch_bounds__(256) void place_bucket_k(
    const int* __restrict__ ei, int* cnt, int2* __restrict__ buckets,
    int4* __restrict__ ovf, int* ovf_cur)
{
    const int t = blockIdx.x * 256 + threadIdx.x;
    if (t * 4 + 3 < N_EDGES) {
        const int4 d4 = ((const int4*)(ei + N_EDGES))[t];
        const int4 s4 = ((const int4*)ei)[t];
        place_one(d4.x, 4 * t + 0, s4.x, cnt, buckets, ovf, ovf_cur);
        place_one(d4.y, 4 * t + 1, s4.y, cnt, buckets, ovf, ovf_cur);
        place_one(d4.z, 4 * t + 2, s4.z, cnt, buckets, ovf, ovf_cur);
        place_one(d4.w, 4 * t + 3, s4.w, cnt, buckets, ovf, ovf_cur);
    } else {
        for (int e = t * 4; e < min(t * 4 + 4, N_EDGES); ++e)
            place_one(ei[N_EDGES + e], e, ei[e], cnt, buckets, ovf, ovf_cur);
    }
}

// ---------------------------------------------------------------------------
// K2 (R8 proven gather + R15 epilogue): 2 nodes/wave, 16 edges/iter, 12
// gathers in flight. x[n] self-rows hoisted to loop-top (hidden). Epilogue
// pre-scales sums by 1/deg, bf16-splits, and stores hi/lo planes k=0..95
// (sums) and k=96..159 (self row, unscaled).
// ---------------------------------------------------------------------------
__global__ __launch_bounds__(256) void aggregate_bucket_k(
    const float* __restrict__ x, const float* __restrict__ ea,
    const int2* __restrict__ buckets, const int* __restrict__ cnt,
    const int4* __restrict__ ovf, const int* __restrict__ ovf_cur,
    unsigned short* __restrict__ ch, unsigned short* __restrict__ cl)
{
    const int lane   = threadIdx.x & 63;
    const int wave   = (blockIdx.x * blockDim.x + threadIdx.x) >> 6;
    const int nwaves = (gridDim.x * blockDim.x) >> 6;

    const int grpx = lane >> 4, colx = lane & 15;  // x: 4 edges/step
    const int grpe = lane >> 3, cole = lane & 7;   // ea: 8 edges/step

    for (int n0 = wave * 2; n0 < N_NODES; n0 += nwaves * 2) {
        const int  nA   = __builtin_amdgcn_readfirstlane(n0);
        const bool hasB = (n0 + 1 < N_NODES);
        const int  nB   = nA + 1;

        // self rows: issue first, consumed only in the epilogue (fully hidden)
        vf4 xsA = {0,0,0,0}, xsB = {0,0,0,0};
        if (lane < 16) {
            xsA = ((const vf4*)(x + (size_t)nA * IN_DIM))[lane];
            if (hasB) xsB = ((const vf4*)(x + (size_t)nB * IN_DIM))[lane];
        }

        const int cFA = __builtin_amdgcn_readfirstlane(cnt[nA]);
        const int cFB = hasB ? __builtin_amdgcn_readfirstlane(cnt[nB]) : 0;
        const int cA  = min(cFA, CAP);
        const int cB  = min(cFB, CAP);

        int eA = 0, srcA = 0, eB = 0, srcB = 0;
        if (lane < cA) {
            const vi2 p = __builtin_nontemporal_load(
                (const vi2*)buckets + (size_t)nA * CAP + lane);
            eA = p.x; srcA = p.y;
        }
        if (lane < cB) {
            const vi2 p = __builtin_nontemporal_load(
                (const vi2*)buckets + (size_t)nB * CAP + lane);
            eB = p.x; srcB = p.y;
        }

        vf4 axA = {0,0,0,0}, aeA = {0,0,0,0};
        vf4 axB = {0,0,0,0}, aeB = {0,0,0,0};

        const int mMax = max(cA, cB);
        for (int j = 0; j < mMax; j += 16) {
            const int jx0 = j +  0 + grpx, jx1 = j +  4 + grpx;
            const int jx2 = j +  8 + grpx, jx3 = j + 12 + grpx;
            const int je0 = j +  0 + grpe, je1 = j +  8 + grpe;
            const int sA0 = __shfl(srcA, jx0), sA1 = __shfl(srcA, jx1);
            const int sA2 = __shfl(srcA, jx2), sA3 = __shfl(srcA, jx3);
            const int sB0 = __shfl(srcB, jx0), sB1 = __shfl(srcB, jx1);
            const int sB2 = __shfl(srcB, jx2), sB3 = __shfl(srcB, jx3);
            const int fA0 = __shfl(eA, je0),   fA1 = __shfl(eA, je1);
            const int fB0 = __shfl(eB, je0),   fB1 = __shfl(eB, je1);

            vf4 xA0 = {0,0,0,0}, xA1 = {0,0,0,0}, xA2 = {0,0,0,0}, xA3 = {0,0,0,0};
            vf4 xB0 = {0,0,0,0}, xB1 = {0,0,0,0}, xB2 = {0,0,0,0}, xB3 = {0,0,0,0};
            vf4 eA0v = {0,0,0,0}, eA1v = {0,0,0,0};
            vf4 eB0v = {0,0,0,0}, eB1v = {0,0,0,0};

            if (jx0 < cA) xA0 = ((const vf4*)(x + (size_t)sA0 * IN_DIM))[colx];
            if (jx1 < cA) xA1 = ((const vf4*)(x + (size_t)sA1 * IN_DIM))[colx];
            if (jx2 < cA) xA2 = ((const vf4*)(x + (size_t)sA2 * IN_DIM))[colx];
            if (jx3 < cA) xA3 = ((const vf4*)(x + (size_t)sA3 * IN_DIM))[colx];
            if (jx0 < cB) xB0 = ((const vf4*)(x + (size_t)sB0 * IN_DIM))[colx];
            if (jx1 < cB) xB1 = ((const vf4*)(x + (size_t)sB1 * IN_DIM))[colx];
            if (jx2 < cB) xB2 = ((const vf4*)(x + (size_t)sB2 * IN_DIM))[colx];
            if (jx3 < cB) xB3 = ((const vf4*)(x + (size_t)sB3 * IN_DIM))[colx];
            if (je0 < cA) eA0v = __builtin_nontemporal_load(
                (const vf4*)(ea + (size_t)fA0 * EDGE_DIM) + cole);
            if (je1 < cA) eA1v = __builtin_nontemporal_load(
                (const vf4*)(ea + (size_t)fA1 * EDGE_DIM) + cole);
            if (je0 < cB) eB0v = __builtin_nontemporal_load(
                (const vf4*)(ea + (size_t)fB0 * EDGE_DIM) + cole);
            if (je1 < cB) eB1v = __builtin_nontemporal_load(
                (const vf4*)(ea + (size_t)fB1 * EDGE_DIM) + cole);

            axA += (xA0 + xA1) + (xA2 + xA3);
            axB += (xB0 + xB1) + (xB2 + xB3);
            aeA += eA0v + eA1v;
            aeB += eB0v + eB1v;
        }

        if (cFA > CAP || cFB > CAP) {
            const int novf = min(__builtin_amdgcn_readfirstlane(*ovf_cur), OVF_CAP);
            for (int i = 0; i < novf; ++i) {
                const int4 v = ovf[i];
                const bool mA = (v.x == nA), mB = hasB && (v.x == nB);
                if (mA || mB) {
                    if (grpx == 0) {
                        const vf4 t = ((const vf4*)(x + (size_t)v.z * IN_DIM))[colx];
                        if (mA) axA += t; else axB += t;
                    }
                    if (grpe == 0) {
                        const vf4 t = ((const vf4*)(ea + (size_t)v.y * EDGE_DIM))[cole];
                        if (mA) aeA += t; else aeB += t;
                    }
                }
            }
        }

#pragma unroll
        for (int mask = 16; mask < 64; mask <<= 1) {
            axA.x += __shfl_xor(axA.x, mask); axA.y += __shfl_xor(axA.y, mask);
            axA.z += __shfl_xor(axA.z, mask); axA.w += __shfl_xor(axA.w, mask);
            axB.x += __shfl_xor(axB.x, mask); axB.y += __shfl_xor(axB.y, mask);
            axB.z += __shfl_xor(axB.z, mask); axB.w += __shfl_xor(axB.w, mask);
        }
#pragma unroll
        for (int mask = 8; mask < 64; mask <<= 1) {
            aeA.x += __shfl_xor(aeA.x, mask); aeA.y += __shfl_xor(aeA.y, mask);
            aeA.z += __shfl_xor(aeA.z, mask); aeA.w += __shfl_xor(aeA.w, mask);
            aeB.x += __shfl_xor(aeB.x, mask); aeB.y += __shfl_xor(aeB.y, mask);
            aeB.z += __shfl_xor(aeB.z, mask); aeB.w += __shfl_xor(aeB.w, mask);
        }

        // epilogue: pre-scale sums by 1/deg, bf16-split; also split self row.
        const float invA = 1.0f / (float)max(cFA, 1);
        const float invB = 1.0f / (float)max(cFB, 1);
        {
            unsigned short* rhA = ch + (size_t)nA * K_CAT;
            unsigned short* rlA = cl + (size_t)nA * K_CAT;
            if (lane < 16) {
                vu4 h, l, hs, ls;
#pragma unroll
                for (int j = 0; j < 4; ++j) {
                    const float v = axA[j] * invA;
                    h[j]  = f2bf(v);      l[j]  = f2bf(v - bf2f(h[j]));
                    hs[j] = f2bf(xsA[j]); ls[j] = f2bf(xsA[j] - bf2f(hs[j]));
                }
                *(vu4*)(rhA + 4 * lane) = h;
                *(vu4*)(rlA + 4 * lane) = l;
                *(vu4*)(rhA + 96 + 4 * lane) = hs;
                *(vu4*)(rlA + 96 + 4 * lane) = ls;
            }
            if (lane < 8) {
                vu4 h, l;
#pragma unroll
                for (int j = 0; j < 4; ++j) {
                    const float v = aeA[j] * invA;
                    h[j] = f2bf(v); l[j] = f2bf(v - bf2f(h[j]));
                }
                *(vu4*)(rhA + 64 + 4 * lane) = h;
                *(vu4*)(rlA + 64 + 4 * lane) = l;
            }
        }
        if (hasB) {
            unsigned short* rhB = ch + (size_t)nB * K_CAT;
            unsigned short* rlB = cl + (size_t)nB * K_CAT;
            if (lane < 16) {
                vu4 h, l, hs, ls;
#pragma unroll
                for (int j = 0; j < 4; ++j) {
                    const float v = axB[j] * invB;
                    h[j]  = f2bf(v);      l[j]  = f2bf(v - bf2f(h[j]));
                    hs[j] = f2bf(xsB[j]); ls[j] = f2bf(xsB[j] - bf2f(hs[j]));
                }
                *(vu4*)(rhB + 4 * lane) = h;
                *(vu4*)(rlB + 4 * lane) = l;
                *(vu4*)(rhB + 96 + 4 * lane) = hs;
                *(vu4*)(rlB + 96 + 4 * lane) = ls;
            }
            if (lane < 8) {
                vu4 h, l;
#pragma unroll
                for (int j = 0; j < 4; ++j) {
                    const float v = aeB[j] * invB;
                    h[j] = f2bf(v); l[j] = f2bf(v - bf2f(h[j]));
                }
                *(vu4*)(rhB + 64 + 4 * lane) = h;
                *(vu4*)(rlB + 64 + 4 * lane) = l;
            }
        }
    }
}

// ---------------------------------------------------------------------------
// K3 (R14 proven): MFMA finalize. out = concat_planes @ [msg_w; self_w] + b.
// Per block: W (hi+lo) swizzled to B-frag order in LDS (40 KB). Per wave:
// 16 nodes x 64 cols; 10 A-frag loads; acc += mfma(ah,bh)+mfma(al,bh)+
// mfma(ah,bl) over 5 k-tiles. A row=lane&15,k=(lane>>4)*8+j; C/D col=lane&15,
// row=(lane>>4)*4+reg (m89-verified).
// ---------------------------------------------------------------------------
__global__ __launch_bounds__(256) void finalize_mfma_k(
    const unsigned short* __restrict__ ch, const unsigned short* __restrict__ cl,
    const int* __restrict__ cnt,
    const float* __restrict__ msg_w, const float* __restrict__ msg_b,
    const float* __restrict__ self_w, const float* __restrict__ self_b,
    float* __restrict__ out)
{
    __shared__ short wfh[1280 * 8];  // [ (ct*5+kt)*64 + lane ][8] hi plane
    __shared__ short wfl[1280 * 8];  // lo plane

    const int tid  = threadIdx.x;
    const int lane = tid & 63;

    for (int idx = tid; idx < 1280; idx += 256) {
        const int ct = idx / 320, rem = idx % 320;
        const int kt = rem / 64,  l   = rem % 64;
        const int c  = ct * 16 + (l & 15);
        const int k0 = kt * 32 + ((l >> 4) << 3);
#pragma unroll
        for (int j = 0; j < 8; ++j) {
            const int k = k0 + j;
            const float w = (k < 96) ? msg_w[k * OUT_DIM + c]
                                     : self_w[(k - 96) * OUT_DIM + c];
            const unsigned short h = f2bf(w);
            wfh[idx * 8 + j] = (short)h;
            wfl[idx * 8 + j] = (short)f2bf(w - bf2f(h));
        }
    }
    __syncthreads();

    float mbv[4], sbv[4];
#pragma unroll
    for (int ct = 0; ct < 4; ++ct) {
        mbv[ct] = msg_b[ct * 16 + (lane & 15)];
        sbv[ct] = self_b[ct * 16 + (lane & 15)];
    }

    const int wid = blockIdx.x * 4 + (tid >> 6);
    const int nw  = gridDim.x * 4;

    for (int t = wid; t < N_NODES / 16; t += nw) {
        const int n0 = t * 16;
        const size_t abase = (size_t)(n0 + (lane & 15)) * K_CAT + ((lane >> 4) << 3);
        bf8 ah[5], al[5];
#pragma unroll
        for (int kt = 0; kt < 5; ++kt) {
            ah[kt] = *(const bf8*)(ch + abase + kt * 32);
            al[kt] = *(const bf8*)(cl + abase + kt * 32);
        }
        int dr[4];
#pragma unroll
        for (int r = 0; r < 4; ++r)
            dr[r] = cnt[n0 + ((lane >> 4) << 2) + r];

        f32x4 acc[4] = {{0,0,0,0},{0,0,0,0},{0,0,0,0},{0,0,0,0}};
#pragma unroll
        for (int kt = 0; kt < 5; ++kt) {
#pragma unroll
            for (int ct = 0; ct < 4; ++ct) {
                const int e = ((ct * 5 + kt) * 64 + lane) * 8;
                const bf8 bh = *(const bf8*)(wfh + e);
                const bf8 bl = *(const bf8*)(wfl + e);
                acc[ct] = __builtin_amdgcn_mfma_f32_16x16x32_bf16(
                    ah[kt], bh, acc[ct], 0, 0, 0);
                acc[ct] = __builtin_amdgcn_mfma_f32_16x16x32_bf16(
                    al[kt], bh, acc[ct], 0, 0, 0);
                acc[ct] = __builtin_amdgcn_mfma_f32_16x16x32_bf16(
                    ah[kt], bl, acc[ct], 0, 0, 0);
            }
        }

#pragma unroll
        for (int ct = 0; ct < 4; ++ct) {
#pragma unroll
            for (int r = 0; r < 4; ++r) {
                const float bsel = (dr[r] > 0) ? 1.0f : 0.0f;
                const int   row  = n0 + ((lane >> 4) << 2) + r;
                out[(size_t)row * OUT_DIM + ct * 16 + (lane & 15)] =
                    acc[ct][r] + mbv[ct] * bsel + sbv[ct];
            }
        }
    }
}

// ---------------------------------------------------------------------------
// Fallback path (small ws): atomic scatter + fp32 finalize (R7 proven).
// ---------------------------------------------------------------------------
__global__ __launch_bounds__(768) void scatter_fb_k(
    const float* __restrict__ x, const int* __restrict__ ei,
    const float* __restrict__ ea, float* sum_x, float* sum_ea, int* deg)
{
    const int t  = threadIdx.x;
    const int el = t / 96;
    const int k  = t - el * 96;
    const int e  = blockIdx.x * 8 + el;
    if (e >= N_EDGES) return;
    const int dst = ei[N_EDGES + e];
    if (k < IN_DIM) {
        const int src = ei[e];
        atomicAdd(&sum_x[dst * IN_DIM + k], x[src * IN_DIM + k]);
        if (k == 0) atomicAdd(&deg[dst], 1);
    } else {
        const int kk = k - IN_DIM;
        atomicAdd(&sum_ea[dst * EDGE_DIM + kk], ea[e * EDGE_DIM + kk]);
    }
}

__global__ __launch_bounds__(64) void finalize64_k(
    const float* __restrict__ x, const float* sum_x_in,
    const float* __restrict__ sum_ea, const int* __restrict__ cnt,
    const float* __restrict__ msg_w, const float* __restrict__ msg_b,
    const float* __restrict__ self_w, const float* __restrict__ self_b,
    float* out)
{
    const int c = threadIdx.x;
    float wm[96], wsf[64];
#pragma unroll
    for (int k = 0; k < 96; ++k) wm[k] = msg_w[k * OUT_DIM + c];
#pragma unroll
    for (int k = 0; k < 64; ++k) wsf[k] = self_w[k * OUT_DIM + c];
    const float mb = msg_b[c];
    const float sb = self_b[c];

    for (int n0 = blockIdx.x; n0 < N_NODES; n0 += gridDim.x) {
        const int n = __builtin_amdgcn_readfirstlane(n0);
        const float4* r1 = (const float4*)(sum_x_in + (size_t)n * IN_DIM);
        const float4* r2 = (const float4*)(sum_ea   + (size_t)n * EDGE_DIM);
        const float4* r3 = (const float4*)(x        + (size_t)n * IN_DIM);
        const int d = cnt[n];
        float am0 = 0.f, am1 = 0.f, am2 = 0.f, am3 = 0.f;
        float as0 = 0.f, as1 = 0.f, as2 = 0.f, as3 = 0.f;
#pragma unroll
        for (int q = 0; q < 16; ++q) {
            const float4 v = r1[q];
            am0 = fmaf(v.x, wm[4 * q + 0], am0);
            am1 = fmaf(v.y, wm[4 * q + 1], am1);
            am2 = fmaf(v.z, wm[4 * q + 2], am2);
            am3 = fmaf(v.w, wm[4 * q + 3], am3);
        }
#pragma unroll
        for (int q = 0; q < 8; ++q) {
            const float4 v = r2[q];
            am0 = fmaf(v.x, wm[64 + 4 * q + 0], am0);
            am1 = fmaf(v.y, wm[64 + 4 * q + 1], am1);
            am2 = fmaf(v.z, wm[64 + 4 * q + 2], am2);
            am3 = fmaf(v.w, wm[64 + 4 * q + 3], am3);
        }
#pragma unroll
        for (int q = 0; q < 16; ++q) {
            const float4 v = r3[q];
            as0 = fmaf(v.x, wsf[4 * q + 0], as0);
            as1 = fmaf(v.y, wsf[4 * q + 1], as1);
            as2 = fmaf(v.z, wsf[4 * q + 2], as2);
            as3 = fmaf(v.w, wsf[4 * q + 3], as3);
        }
        const float inv  = 1.0f / (float)max(d, 1);
        const float bsel = (d > 0) ? 1.0f : 0.0f;
        out[(size_t)n * OUT_DIM + c] =
            ((as0 + as1) + (as2 + as3)) + sb +
            ((am0 + am1) + (am2 + am3)) * inv + mb * bsel;
    }
}

// ---------------------------------------------------------------------------
extern "C" void kernel_launch(void* const* d_in, const int* in_sizes, int n_in,
                              void* d_out, int out_size, void* d_ws, size_t ws_size,
                              hipStream_t stream) {
    const float* x      = (const float*)d_in[0];
    const int*   ei     = (const int*)d_in[1];   // [2][E]
    const float* ea     = (const float*)d_in[2];
    const float* msg_w  = (const float*)d_in[3];
    const float* msg_b  = (const float*)d_in[4];
    const float* self_w = (const float*)d_in[5];
    const float* self_b = (const float*)d_in[6];

    float* out = (float*)d_out;

    // ws layout:
    //   cnt[50000] int | ovf_cur[1] | pad16 | buckets[50000*CAP int2]
    //   | ovf[OVF_CAP int4] | ch[50000*160 ushort] | cl[50000*160 ushort]
    int*            cnt     = (int*)d_ws;
    int*            ovf_cur = cnt + N_NODES;
    int2*           buckets = (int2*)(cnt + N_NODES + 16);
    int4*           ovf     = (int4*)(buckets + (size_t)N_NODES * CAP);
    unsigned short* ch      = (unsigned short*)(ovf + OVF_CAP);
    unsigned short* cl      = ch + (size_t)N_NODES * K_CAT;
    const size_t need_bucket =
        ((size_t)N_NODES + 16 + 2 * (size_t)N_NODES * CAP + 4 * (size_t)OVF_CAP) *
            sizeof(int) +
        2 * (size_t)N_NODES * K_CAT * sizeof(unsigned short);

    if (ws_size >= need_bucket) {
        hipMemsetAsync(cnt, 0, (N_NODES + 16) * sizeof(int), stream);
        place_bucket_k<<<(N_EDGES / 4 + 255) / 256, 256, 0, stream>>>(
            ei, cnt, buckets, ovf, ovf_cur);
        aggregate_bucket_k<<<(N_NODES / 2 + 3) / 4, 256, 0, stream>>>(
            x, ea, buckets, cnt, ovf, ovf_cur, ch, cl);
        finalize_mfma_k<<<(N_NODES / 16 + 3) / 4, 256, 0, stream>>>(
            ch, cl, cnt, msg_w, msg_b, self_w, self_b, out);
    } else {
        // Fallback: fp32 atomic scatter + fp32 finalize
        float* fb_sum_x  = (float*)d_ws;
        float* fb_sum_ea = fb_sum_x + (size_t)N_NODES * IN_DIM;
        int*   deg       = (int*)(fb_sum_ea + (size_t)N_NODES * EDGE_DIM);
        hipMemsetAsync(d_ws, 0,
                       (size_t)N_NODES * (IN_DIM + EDGE_DIM + 1) * sizeof(float),
                       stream);
        scatter_fb_k<<<(N_EDGES + 7) / 8, 768, 0, stream>>>(
            x, ei, ea, fb_sum_x, fb_sum_ea, deg);
        finalize64_k<<<4096, 64, 0, stream>>>(
            x, fb_sum_x, fb_sum_ea, deg, msg_w, msg_b, self_w, self_b, out);
    }
}

// Round 10
// 260.355 us; speedup vs baseline: 1.2764x; 1.0033x over previous
//
#include <hip/hip_runtime.h>

// EdgeSageLayer on MI355X — round 17 (R16 resubmit; prior bench was an
// infra failure: "container failed twice", no counters. Kernel audited:
// cnt indexing/memset/ws-size all in bounds; no launch-API violations).
// agg[n] = (sum_{e:dst=n} concat(x[src_e], ea_e)) @ msg_w / deg + msg_b*(deg>0)
// R15 state: BEST total 261us = place 61 + aggregate ~50 + finalize_mfma ~10.
// place counters: VALU 0.35%, HBM 11%, FETCH 3.3MB -- pure wait. Suspects:
// (1) 4 sequential atomicAdd round trips per thread, (2) cnt packed 16
// counters/64B-line -> ~256 serialized atomics per line.
// R16/17: (a) phase-split place: 4 independent atomicAdds issued
// back-to-back (one wait), then 4 stores -> 4x MLP on the chain. (b) pad cnt
// to one counter per 64B line (CPAD=16). If place doesn't move -> it's at
// the random-64B-burst floor and is declared done.
// aggregate (R8 gather + bf16-plane epilogue) and finalize (bf16-split MFMA)
// unchanged.

constexpr int N_NODES  = 50000;
constexpr int N_EDGES  = 800000;
constexpr int IN_DIM   = 64;
constexpr int EDGE_DIM = 32;
constexpr int OUT_DIM  = 64;
constexpr int K_CAT    = 160;     // 64 sum_x + 32 sum_ea + 64 x
constexpr int CAP      = 48;      // bucket capacity; Poisson(16) max deg ~40
constexpr int OVF_CAP  = 65536;   // overflow list capacity (deg>CAP tails)
constexpr int CPAD     = 16;      // cnt stride: 1 counter per 64B line

using vf4   = __attribute__((ext_vector_type(4))) float;
using vi2   = __attribute__((ext_vector_type(2))) int;
using vu4   = __attribute__((ext_vector_type(4))) unsigned short;
using bf8   = __attribute__((ext_vector_type(8))) short;   // 8 bf16 (4 VGPR)
using f32x4 = __attribute__((ext_vector_type(4))) float;

__device__ __forceinline__ unsigned short f2bf(float f) {   // RNE
    unsigned int u = __float_as_uint(f);
    return (unsigned short)((u + 0x7fffu + ((u >> 16) & 1u)) >> 16);
}
__device__ __forceinline__ float bf2f(unsigned short h) {
    return __uint_as_float(((unsigned int)h) << 16);
}

// ---------------------------------------------------------------------------
// K1: phase-split bucket build. 4 independent atomicAdds (padded cnt)
// issued before any dependent store; rare pos>=CAP goes to the overflow list.
// ---------------------------------------------------------------------------
__device__ __forceinline__ void store_one(int dst, int e, int src, int pos,
                                          int2* buckets, int4* ovf,
                                          int* ovf_cur) {
    if (pos < CAP) {
        buckets[(size_t)dst * CAP + pos] = make_int2(e, src);
    } else {
        const int o = atomicAdd(ovf_cur, 1);
        if (o < OVF_CAP) ovf[o] = make_int4(dst, e, src, 0);
    }
}

__global__ __launch_bounds__(256) void place_bucket_k(
    const int* __restrict__ ei, int* cnt, int2* __restrict__ buckets,
    int4* __restrict__ ovf, int* ovf_cur)
{
    const int t = blockIdx.x * 256 + threadIdx.x;
    if (t * 4 + 3 < N_EDGES) {
        const int4 d4 = ((const int4*)(ei + N_EDGES))[t];
        const int4 s4 = ((const int4*)ei)[t];
        // phase 1: 4 independent atomic round trips in flight
        const int p0 = atomicAdd(&cnt[(size_t)d4.x * CPAD], 1);
        const int p1 = atomicAdd(&cnt[(size_t)d4.y * CPAD], 1);
        const int p2 = atomicAdd(&cnt[(size_t)d4.z * CPAD], 1);
        const int p3 = atomicAdd(&cnt[(size_t)d4.w * CPAD], 1);
        // phase 2: dependent stores
        store_one(d4.x, 4 * t + 0, s4.x, p0, buckets, ovf, ovf_cur);
        store_one(d4.y, 4 * t + 1, s4.y, p1, buckets, ovf, ovf_cur);
        store_one(d4.z, 4 * t + 2, s4.z, p2, buckets, ovf, ovf_cur);
        store_one(d4.w, 4 * t + 3, s4.w, p3, buckets, ovf, ovf_cur);
    } else {
        for (int e = t * 4; e < min(t * 4 + 4, N_EDGES); ++e) {
            const int dst = ei[N_EDGES + e];
            const int pos = atomicAdd(&cnt[(size_t)dst * CPAD], 1);
            store_one(dst, e, ei[e], pos, buckets, ovf, ovf_cur);
        }
    }
}

// ---------------------------------------------------------------------------
// K2 (R8 proven gather + R15 epilogue): 2 nodes/wave, 16 edges/iter, 12
// gathers in flight. x[n] self-rows hoisted to loop-top (hidden). Epilogue
// pre-scales sums by 1/deg, bf16-splits, stores hi/lo planes k=0..95 (sums)
// and k=96..159 (self row, unscaled).
// ---------------------------------------------------------------------------
__global__ __launch_bounds__(256) void aggregate_bucket_k(
    const float* __restrict__ x, const float* __restrict__ ea,
    const int2* __restrict__ buckets, const int* __restrict__ cnt,
    const int4* __restrict__ ovf, const int* __restrict__ ovf_cur,
    unsigned short* __restrict__ ch, unsigned short* __restrict__ cl)
{
    const int lane   = threadIdx.x & 63;
    const int wave   = (blockIdx.x * blockDim.x + threadIdx.x) >> 6;
    const int nwaves = (gridDim.x * blockDim.x) >> 6;

    const int grpx = lane >> 4, colx = lane & 15;  // x: 4 edges/step
    const int grpe = lane >> 3, cole = lane & 7;   // ea: 8 edges/step

    for (int n0 = wave * 2; n0 < N_NODES; n0 += nwaves * 2) {
        const int  nA   = __builtin_amdgcn_readfirstlane(n0);
        const bool hasB = (n0 + 1 < N_NODES);
        const int  nB   = nA + 1;

        // self rows: issue first, consumed only in the epilogue (fully hidden)
        vf4 xsA = {0,0,0,0}, xsB = {0,0,0,0};
        if (lane < 16) {
            xsA = ((const vf4*)(x + (size_t)nA * IN_DIM))[lane];
            if (hasB) xsB = ((const vf4*)(x + (size_t)nB * IN_DIM))[lane];
        }

        const int cFA = __builtin_amdgcn_readfirstlane(cnt[(size_t)nA * CPAD]);
        const int cFB = hasB ? __builtin_amdgcn_readfirstlane(cnt[(size_t)nB * CPAD]) : 0;
        const int cA  = min(cFA, CAP);
        const int cB  = min(cFB, CAP);

        int eA = 0, srcA = 0, eB = 0, srcB = 0;
        if (lane < cA) {
            const vi2 p = __builtin_nontemporal_load(
                (const vi2*)buckets + (size_t)nA * CAP + lane);
            eA = p.x; srcA = p.y;
        }
        if (lane < cB) {
            const vi2 p = __builtin_nontemporal_load(
                (const vi2*)buckets + (size_t)nB * CAP + lane);
            eB = p.x; srcB = p.y;
        }

        vf4 axA = {0,0,0,0}, aeA = {0,0,0,0};
        vf4 axB = {0,0,0,0}, aeB = {0,0,0,0};

        const int mMax = max(cA, cB);
        for (int j = 0; j < mMax; j += 16) {
            const int jx0 = j +  0 + grpx, jx1 = j +  4 + grpx;
            const int jx2 = j +  8 + grpx, jx3 = j + 12 + grpx;
            const int je0 = j +  0 + grpe, je1 = j +  8 + grpe;
            const int sA0 = __shfl(srcA, jx0), sA1 = __shfl(srcA, jx1);
            const int sA2 = __shfl(srcA, jx2), sA3 = __shfl(srcA, jx3);
            const int sB0 = __shfl(srcB, jx0), sB1 = __shfl(srcB, jx1);
            const int sB2 = __shfl(srcB, jx2), sB3 = __shfl(srcB, jx3);
            const int fA0 = __shfl(eA, je0),   fA1 = __shfl(eA, je1);
            const int fB0 = __shfl(eB, je0),   fB1 = __shfl(eB, je1);

            vf4 xA0 = {0,0,0,0}, xA1 = {0,0,0,0}, xA2 = {0,0,0,0}, xA3 = {0,0,0,0};
            vf4 xB0 = {0,0,0,0}, xB1 = {0,0,0,0}, xB2 = {0,0,0,0}, xB3 = {0,0,0,0};
            vf4 eA0v = {0,0,0,0}, eA1v = {0,0,0,0};
            vf4 eB0v = {0,0,0,0}, eB1v = {0,0,0,0};

            if (jx0 < cA) xA0 = ((const vf4*)(x + (size_t)sA0 * IN_DIM))[colx];
            if (jx1 < cA) xA1 = ((const vf4*)(x + (size_t)sA1 * IN_DIM))[colx];
            if (jx2 < cA) xA2 = ((const vf4*)(x + (size_t)sA2 * IN_DIM))[colx];
            if (jx3 < cA) xA3 = ((const vf4*)(x + (size_t)sA3 * IN_DIM))[colx];
            if (jx0 < cB) xB0 = ((const vf4*)(x + (size_t)sB0 * IN_DIM))[colx];
            if (jx1 < cB) xB1 = ((const vf4*)(x + (size_t)sB1 * IN_DIM))[colx];
            if (jx2 < cB) xB2 = ((const vf4*)(x + (size_t)sB2 * IN_DIM))[colx];
            if (jx3 < cB) xB3 = ((const vf4*)(x + (size_t)sB3 * IN_DIM))[colx];
            if (je0 < cA) eA0v = __builtin_nontemporal_load(
                (const vf4*)(ea + (size_t)fA0 * EDGE_DIM) + cole);
            if (je1 < cA) eA1v = __builtin_nontemporal_load(
                (const vf4*)(ea + (size_t)fA1 * EDGE_DIM) + cole);
            if (je0 < cB) eB0v = __builtin_nontemporal_load(
                (const vf4*)(ea + (size_t)fB0 * EDGE_DIM) + cole);
            if (je1 < cB) eB1v = __builtin_nontemporal_load(
                (const vf4*)(ea + (size_t)fB1 * EDGE_DIM) + cole);

            axA += (xA0 + xA1) + (xA2 + xA3);
            axB += (xB0 + xB1) + (xB2 + xB3);
            aeA += eA0v + eA1v;
            aeB += eB0v + eB1v;
        }

        if (cFA > CAP || cFB > CAP) {
            const int novf = min(__builtin_amdgcn_readfirstlane(*ovf_cur), OVF_CAP);
            for (int i = 0; i < novf; ++i) {
                const int4 v = ovf[i];
                const bool mA = (v.x == nA), mB = hasB && (v.x == nB);
                if (mA || mB) {
                    if (grpx == 0) {
                        const vf4 t = ((const vf4*)(x + (size_t)v.z * IN_DIM))[colx];
                        if (mA) axA += t; else axB += t;
                    }
                    if (grpe == 0) {
                        const vf4 t = ((const vf4*)(ea + (size_t)v.y * EDGE_DIM))[cole];
                        if (mA) aeA += t; else aeB += t;
                    }
                }
            }
        }

#pragma unroll
        for (int mask = 16; mask < 64; mask <<= 1) {
            axA.x += __shfl_xor(axA.x, mask); axA.y += __shfl_xor(axA.y, mask);
            axA.z += __shfl_xor(axA.z, mask); axA.w += __shfl_xor(axA.w, mask);
            axB.x += __shfl_xor(axB.x, mask); axB.y += __shfl_xor(axB.y, mask);
            axB.z += __shfl_xor(axB.z, mask); axB.w += __shfl_xor(axB.w, mask);
        }
#pragma unroll
        for (int mask = 8; mask < 64; mask <<= 1) {
            aeA.x += __shfl_xor(aeA.x, mask); aeA.y += __shfl_xor(aeA.y, mask);
            aeA.z += __shfl_xor(aeA.z, mask); aeA.w += __shfl_xor(aeA.w, mask);
            aeB.x += __shfl_xor(aeB.x, mask); aeB.y += __shfl_xor(aeB.y, mask);
            aeB.z += __shfl_xor(aeB.z, mask); aeB.w += __shfl_xor(aeB.w, mask);
        }

        // epilogue: pre-scale sums by 1/deg, bf16-split; also split self row.
        const float invA = 1.0f / (float)max(cFA, 1);
        const float invB = 1.0f / (float)max(cFB, 1);
        {
            unsigned short* rhA = ch + (size_t)nA * K_CAT;
            unsigned short* rlA = cl + (size_t)nA * K_CAT;
            if (lane < 16) {
                vu4 h, l, hs, ls;
#pragma unroll
                for (int j = 0; j < 4; ++j) {
                    const float v = axA[j] * invA;
                    h[j]  = f2bf(v);      l[j]  = f2bf(v - bf2f(h[j]));
                    hs[j] = f2bf(xsA[j]); ls[j] = f2bf(xsA[j] - bf2f(hs[j]));
                }
                *(vu4*)(rhA + 4 * lane) = h;
                *(vu4*)(rlA + 4 * lane) = l;
                *(vu4*)(rhA + 96 + 4 * lane) = hs;
                *(vu4*)(rlA + 96 + 4 * lane) = ls;
            }
            if (lane < 8) {
                vu4 h, l;
#pragma unroll
                for (int j = 0; j < 4; ++j) {
                    const float v = aeA[j] * invA;
                    h[j] = f2bf(v); l[j] = f2bf(v - bf2f(h[j]));
                }
                *(vu4*)(rhA + 64 + 4 * lane) = h;
                *(vu4*)(rlA + 64 + 4 * lane) = l;
            }
        }
        if (hasB) {
            unsigned short* rhB = ch + (size_t)nB * K_CAT;
            unsigned short* rlB = cl + (size_t)nB * K_CAT;
            if (lane < 16) {
                vu4 h, l, hs, ls;
#pragma unroll
                for (int j = 0; j < 4; ++j) {
                    const float v = axB[j] * invB;
                    h[j]  = f2bf(v);      l[j]  = f2bf(v - bf2f(h[j]));
                    hs[j] = f2bf(xsB[j]); ls[j] = f2bf(xsB[j] - bf2f(hs[j]));
                }
                *(vu4*)(rhB + 4 * lane) = h;
                *(vu4*)(rlB + 4 * lane) = l;
                *(vu4*)(rhB + 96 + 4 * lane) = hs;
                *(vu4*)(rlB + 96 + 4 * lane) = ls;
            }
            if (lane < 8) {
                vu4 h, l;
#pragma unroll
                for (int j = 0; j < 4; ++j) {
                    const float v = aeB[j] * invB;
                    h[j] = f2bf(v); l[j] = f2bf(v - bf2f(h[j]));
                }
                *(vu4*)(rhB + 64 + 4 * lane) = h;
                *(vu4*)(rlB + 64 + 4 * lane) = l;
            }
        }
    }
}

// ---------------------------------------------------------------------------
// K3 (R14 proven): MFMA finalize. out = concat_planes @ [msg_w; self_w] + b.
// ---------------------------------------------------------------------------
__global__ __launch_bounds__(256) void finalize_mfma_k(
    const unsigned short* __restrict__ ch, const unsigned short* __restrict__ cl,
    const int* __restrict__ cnt,
    const float* __restrict__ msg_w, const float* __restrict__ msg_b,
    const float* __restrict__ self_w, const float* __restrict__ self_b,
    float* __restrict__ out)
{
    __shared__ short wfh[1280 * 8];  // [ (ct*5+kt)*64 + lane ][8] hi plane
    __shared__ short wfl[1280 * 8];  // lo plane

    const int tid  = threadIdx.x;
    const int lane = tid & 63;

    for (int idx = tid; idx < 1280; idx += 256) {
        const int ct = idx / 320, rem = idx % 320;
        const int kt = rem / 64,  l   = rem % 64;
        const int c  = ct * 16 + (l & 15);
        const int k0 = kt * 32 + ((l >> 4) << 3);
#pragma unroll
        for (int j = 0; j < 8; ++j) {
            const int k = k0 + j;
            const float w = (k < 96) ? msg_w[k * OUT_DIM + c]
                                     : self_w[(k - 96) * OUT_DIM + c];
            const unsigned short h = f2bf(w);
            wfh[idx * 8 + j] = (short)h;
            wfl[idx * 8 + j] = (short)f2bf(w - bf2f(h));
        }
    }
    __syncthreads();

    float mbv[4], sbv[4];
#pragma unroll
    for (int ct = 0; ct < 4; ++ct) {
        mbv[ct] = msg_b[ct * 16 + (lane & 15)];
        sbv[ct] = self_b[ct * 16 + (lane & 15)];
    }

    const int wid = blockIdx.x * 4 + (tid >> 6);
    const int nw  = gridDim.x * 4;

    for (int t = wid; t < N_NODES / 16; t += nw) {
        const int n0 = t * 16;
        const size_t abase = (size_t)(n0 + (lane & 15)) * K_CAT + ((lane >> 4) << 3);
        bf8 ah[5], al[5];
#pragma unroll
        for (int kt = 0; kt < 5; ++kt) {
            ah[kt] = *(const bf8*)(ch + abase + kt * 32);
            al[kt] = *(const bf8*)(cl + abase + kt * 32);
        }
        int dr[4];
#pragma unroll
        for (int r = 0; r < 4; ++r)
            dr[r] = cnt[(size_t)(n0 + ((lane >> 4) << 2) + r) * CPAD];

        f32x4 acc[4] = {{0,0,0,0},{0,0,0,0},{0,0,0,0},{0,0,0,0}};
#pragma unroll
        for (int kt = 0; kt < 5; ++kt) {
#pragma unroll
            for (int ct = 0; ct < 4; ++ct) {
                const int e = ((ct * 5 + kt) * 64 + lane) * 8;
                const bf8 bh = *(const bf8*)(wfh + e);
                const bf8 bl = *(const bf8*)(wfl + e);
                acc[ct] = __builtin_amdgcn_mfma_f32_16x16x32_bf16(
                    ah[kt], bh, acc[ct], 0, 0, 0);
                acc[ct] = __builtin_amdgcn_mfma_f32_16x16x32_bf16(
                    al[kt], bh, acc[ct], 0, 0, 0);
                acc[ct] = __builtin_amdgcn_mfma_f32_16x16x32_bf16(
                    ah[kt], bl, acc[ct], 0, 0, 0);
            }
        }

#pragma unroll
        for (int ct = 0; ct < 4; ++ct) {
#pragma unroll
            for (int r = 0; r < 4; ++r) {
                const float bsel = (dr[r] > 0) ? 1.0f : 0.0f;
                const int   row  = n0 + ((lane >> 4) << 2) + r;
                out[(size_t)row * OUT_DIM + ct * 16 + (lane & 15)] =
                    acc[ct][r] + mbv[ct] * bsel + sbv[ct];
            }
        }
    }
}

// ---------------------------------------------------------------------------
// Fallback path (small ws): atomic scatter + fp32 finalize (R7 proven).
// ---------------------------------------------------------------------------
__global__ __launch_bounds__(768) void scatter_fb_k(
    const float* __restrict__ x, const int* __restrict__ ei,
    const float* __restrict__ ea, float* sum_x, float* sum_ea, int* deg)
{
    const int t  = threadIdx.x;
    const int el = t / 96;
    const int k  = t - el * 96;
    const int e  = blockIdx.x * 8 + el;
    if (e >= N_EDGES) return;
    const int dst = ei[N_EDGES + e];
    if (k < IN_DIM) {
        const int src = ei[e];
        atomicAdd(&sum_x[dst * IN_DIM + k], x[src * IN_DIM + k]);
        if (k == 0) atomicAdd(&deg[dst], 1);
    } else {
        const int kk = k - IN_DIM;
        atomicAdd(&sum_ea[dst * EDGE_DIM + kk], ea[e * EDGE_DIM + kk]);
    }
}

__global__ __launch_bounds__(64) void finalize64_k(
    const float* __restrict__ x, const float* sum_x_in,
    const float* __restrict__ sum_ea, const int* __restrict__ cnt,
    const float* __restrict__ msg_w, const float* __restrict__ msg_b,
    const float* __restrict__ self_w, const float* __restrict__ self_b,
    float* out)
{
    const int c = threadIdx.x;
    float wm[96], wsf[64];
#pragma unroll
    for (int k = 0; k < 96; ++k) wm[k] = msg_w[k * OUT_DIM + c];
#pragma unroll
    for (int k = 0; k < 64; ++k) wsf[k] = self_w[k * OUT_DIM + c];
    const float mb = msg_b[c];
    const float sb = self_b[c];

    for (int n0 = blockIdx.x; n0 < N_NODES; n0 += gridDim.x) {
        const int n = __builtin_amdgcn_readfirstlane(n0);
        const float4* r1 = (const float4*)(sum_x_in + (size_t)n * IN_DIM);
        const float4* r2 = (const float4*)(sum_ea   + (size_t)n * EDGE_DIM);
        const float4* r3 = (const float4*)(x        + (size_t)n * IN_DIM);
        const int d = cnt[n];
        float am0 = 0.f, am1 = 0.f, am2 = 0.f, am3 = 0.f;
        float as0 = 0.f, as1 = 0.f, as2 = 0.f, as3 = 0.f;
#pragma unroll
        for (int q = 0; q < 16; ++q) {
            const float4 v = r1[q];
            am0 = fmaf(v.x, wm[4 * q + 0], am0);
            am1 = fmaf(v.y, wm[4 * q + 1], am1);
            am2 = fmaf(v.z, wm[4 * q + 2], am2);
            am3 = fmaf(v.w, wm[4 * q + 3], am3);
        }
#pragma unroll
        for (int q = 0; q < 8; ++q) {
            const float4 v = r2[q];
            am0 = fmaf(v.x, wm[64 + 4 * q + 0], am0);
            am1 = fmaf(v.y, wm[64 + 4 * q + 1], am1);
            am2 = fmaf(v.z, wm[64 + 4 * q + 2], am2);
            am3 = fmaf(v.w, wm[64 + 4 * q + 3], am3);
        }
#pragma unroll
        for (int q = 0; q < 16; ++q) {
            const float4 v = r3[q];
            as0 = fmaf(v.x, wsf[4 * q + 0], as0);
            as1 = fmaf(v.y, wsf[4 * q + 1], as1);
            as2 = fmaf(v.z, wsf[4 * q + 2], as2);
            as3 = fmaf(v.w, wsf[4 * q + 3], as3);
        }
        const float inv  = 1.0f / (float)max(d, 1);
        const float bsel = (d > 0) ? 1.0f : 0.0f;
        out[(size_t)n * OUT_DIM + c] =
            ((as0 + as1) + (as2 + as3)) + sb +
            ((am0 + am1) + (am2 + am3)) * inv + mb * bsel;
    }
}

// ---------------------------------------------------------------------------
extern "C" void kernel_launch(void* const* d_in, const int* in_sizes, int n_in,
                              void* d_out, int out_size, void* d_ws, size_t ws_size,
                              hipStream_t stream) {
    const float* x      = (const float*)d_in[0];
    const int*   ei     = (const int*)d_in[1];   // [2][E]
    const float* ea     = (const float*)d_in[2];
    const float* msg_w  = (const float*)d_in[3];
    const float* msg_b  = (const float*)d_in[4];
    const float* self_w = (const float*)d_in[5];
    const float* self_b = (const float*)d_in[6];

    float* out = (float*)d_out;

    // ws layout:
    //   cnt[50000*CPAD] int | ovf_cur[1] | pad16 | buckets[50000*CAP int2]
    //   | ovf[OVF_CAP int4] | ch[50000*160 ushort] | cl[50000*160 ushort]
    int*            cnt     = (int*)d_ws;
    int*            ovf_cur = cnt + (size_t)N_NODES * CPAD;
    int2*           buckets = (int2*)(ovf_cur + 16);
    int4*           ovf     = (int4*)(buckets + (size_t)N_NODES * CAP);
    unsigned short* ch      = (unsigned short*)(ovf + OVF_CAP);
    unsigned short* cl      = ch + (size_t)N_NODES * K_CAT;
    const size_t need_bucket =
        ((size_t)N_NODES * CPAD + 16 + 2 * (size_t)N_NODES * CAP +
         4 * (size_t)OVF_CAP) * sizeof(int) +
        2 * (size_t)N_NODES * K_CAT * sizeof(unsigned short);

    if (ws_size >= need_bucket) {
        hipMemsetAsync(cnt, 0, ((size_t)N_NODES * CPAD + 16) * sizeof(int),
                       stream);
        place_bucket_k<<<(N_EDGES / 4 + 255) / 256, 256, 0, stream>>>(
            ei, cnt, buckets, ovf, ovf_cur);
        aggregate_bucket_k<<<(N_NODES / 2 + 3) / 4, 256, 0, stream>>>(
            x, ea, buckets, cnt, ovf, ovf_cur, ch, cl);
        finalize_mfma_k<<<(N_NODES / 16 + 3) / 4, 256, 0, stream>>>(
            ch, cl, cnt, msg_w, msg_b, self_w, self_b, out);
    } else {
        // Fallback: fp32 atomic scatter + fp32 finalize
        float* fb_sum_x  = (float*)d_ws;
        float* fb_sum_ea = fb_sum_x + (size_t)N_NODES * IN_DIM;
        int*   deg       = (int*)(fb_sum_ea + (size_t)N_NODES * EDGE_DIM);
        hipMemsetAsync(d_ws, 0,
                       (size_t)N_NODES * (IN_DIM + EDGE_DIM + 1) * sizeof(float),
                       stream);
        scatter_fb_k<<<(N_EDGES + 7) / 8, 768, 0, stream>>>(
            x, ei, ea, fb_sum_x, fb_sum_ea, deg);
        finalize64_k<<<4096, 64, 0, stream>>>(
            x, fb_sum_x, fb_sum_ea, deg, msg_w, msg_b, self_w, self_b, out);
    }
}